// Round 5
// baseline (472.797 us; speedup 1.0000x reference)
//
#include <hip/hip_runtime.h>

#define N_PTS 100000
#define NT_STRIDE 100096            // padded row count for nbrsT
#define NK 27
#define NKP 28                      // k rows incl. dummy zero slot k=27
#define TOTAL (N_PTS * 64)          // 6400000
#define NB_CONV 1564                // grid: 1564 blocks * 64 rows

typedef short bf16x8 __attribute__((ext_vector_type(8)));   // 8 bf16 in 4 VGPRs
typedef float f32x4 __attribute__((ext_vector_type(4)));
typedef unsigned short u16x8 __attribute__((ext_vector_type(8)));

__device__ __forceinline__ unsigned short f2bf(float f) {
    unsigned u = __builtin_bit_cast(unsigned, f);
    u += 0x7fffu + ((u >> 16) & 1u);           // round-to-nearest-even
    return (unsigned short)(u >> 16);
}
__device__ __forceinline__ float bf2f(unsigned short u) {
    return __builtin_bit_cast(float, ((unsigned)u) << 16);
}

// ---------------- cast feats -> bf16, plus zeroed pad row at index N_PTS ----------------
__global__ void cast_in_k(const float* __restrict__ feats, unsigned short* __restrict__ xb) {
    int t = blockIdx.x * 256 + threadIdx.x;
    if (t >= (N_PTS + 1) * 8) return;
    int i = t * 8;
    u16x8 o;
    if (i < TOTAL) {
        f32x4 v0 = ((const f32x4*)(feats + i))[0];
        f32x4 v1 = ((const f32x4*)(feats + i))[1];
#pragma unroll
        for (int j = 0; j < 4; ++j) { o[j] = f2bf(v0[j]); o[4 + j] = f2bf(v1[j]); }
    } else {
#pragma unroll
        for (int j = 0; j < 8; ++j) o[j] = 0;
    }
    *(u16x8*)(xb + i) = o;
}

// ---------------- transpose rulebook: nbrsT[k][n] = nbrs[n][k]; k=27 row & pad rows -> N_PTS ----------------
__global__ void tr_nbrs_k(const int* __restrict__ nbrs, int* __restrict__ nbrsT) {
    __shared__ int tile[64 * 28];
    const int n0 = blockIdx.x * 64;
    const int t = threadIdx.x;
    const int base = n0 * 27;
    for (int i = t; i < 1728; i += 256) {
        int v = (base + i < N_PTS * 27) ? nbrs[base + i] : N_PTS;
        int r = i / 27, c = i - r * 27;
        tile[r * 28 + c] = v;
    }
    __syncthreads();
    for (int i = t; i < 1728; i += 256) {
        int k = i >> 6, j = i & 63;                        // k 0..26
        nbrsT[(size_t)k * NT_STRIDE + n0 + j] = tile[j * 28 + k];
    }
    for (int i = t; i < 64; i += 256)                      // dummy k=27 row -> pad
        nbrsT[(size_t)27 * NT_STRIDE + n0 + i] = N_PTS;
}

// ---------------- pack W -> bf16 MFMA-B-fragment order, 28 k-slots/conv (k=27 zeroed) ----------------
// Wp layout: [conv][k(28)][kk][cb][lane][8]; frag elem j is B[c = kk*32+(lane>>4)*8+j, d = cb*16+(lane&15)]
__global__ void pack_w_k(const float* __restrict__ W, unsigned short* __restrict__ Wp) {
    int o = blockIdx.x * 256 + threadIdx.x;
    if (o >= 4 * NKP * 4096) return;
    int conv = o / (NKP * 4096);
    int r = o - conv * (NKP * 4096);
    int k = r >> 12;
    if (k == 27) { Wp[o] = 0; return; }
    int r2 = r & 4095;
    int frag = r2 >> 9;
    int kk = frag >> 2, cb = frag & 3;
    int lane = (r2 >> 3) & 63;
    int j = r2 & 7;
    int c = kk * 32 + (lane >> 4) * 8 + j;
    int d = cb * 16 + (lane & 15);
    Wp[o] = f2bf(W[(size_t)(conv * NK + k) * 4096 + c * 64 + d]);
}

// ---------------- gather-GEMM conv, K-split across wave pairs ----------------
// 4 waves/block = 2 rowhalves (32 rows) x 2 khalves (14 k-steps each; kh=1 includes zero dummy k=27).
// idx window 4, A-gather prefetch depth 2, sched_barrier pins prefetch issue ahead of MFMAs.
// K-halves reduced through LDS f32 tile; tile read-out produces bf16 y + per-channel sums.
__global__ __launch_bounds__(256, 4) void conv_k(
    const unsigned short* __restrict__ xb,     // [N_PTS+1][64] bf16
    const int* __restrict__ nbrsT,             // [28][NT_STRIDE]
    const unsigned short* __restrict__ Wp,     // packed fragments for this conv (28 k-slots)
    unsigned short* __restrict__ ybf,          // [N_PTS][64] bf16
    float* __restrict__ partials)              // [NB_CONV][128]
{
    const int tid = threadIdx.x;
    const int lane = tid & 63;
    const int wave = tid >> 6;
    const int l15 = lane & 15;
    const int lgrp = lane >> 4;
    const int h = wave & 1;                    // rowhalf
    const int kh = wave >> 1;                  // khalf
    const int wave_row = blockIdx.x * 64 + h * 32;
    const int r0 = wave_row + l15;             // < NT_STRIDE always
    const int r1 = r0 + 16;
    const int k0 = kh * 14;                    // kh=0: k 0..13 ; kh=1: k 14..27 (27 = zeros)

    f32x4 acc[2][4];
#pragma unroll
    for (int m = 0; m < 2; ++m)
#pragma unroll
        for (int cb = 0; cb < 4; ++cb) acc[m][cb] = (f32x4)0.f;

    const bf16x8* wp = (const bf16x8*)Wp;

    // idx pipeline: window of 4 per row-half
    int id0[4], id1[4];
#pragma unroll
    for (int s = 0; s < 4; ++s) {
        id0[s] = nbrsT[(size_t)(k0 + s) * NT_STRIDE + r0];
        id1[s] = nbrsT[(size_t)(k0 + s) * NT_STRIDE + r1];
    }
    // A pipeline: 3 stages x 4 frags ([0]=row0 c0-31, [1]=row0 c32-63, [2]=row1 c0-31, [3]=row1 c32-63)
    bf16x8 apf[3][4];
#pragma unroll
    for (int s = 0; s < 2; ++s) {
        const bf16x8* p0 = (const bf16x8*)(xb + (size_t)id0[s] * 64);
        const bf16x8* p1 = (const bf16x8*)(xb + (size_t)id1[s] * 64);
        apf[s][0] = p0[lgrp]; apf[s][1] = p0[4 + lgrp];
        apf[s][2] = p1[lgrp]; apf[s][3] = p1[4 + lgrp];
    }

#pragma unroll
    for (int s = 0; s < 14; ++s) {
        if (s + 4 < 14) {                      // idx prefetch (coalesced)
            id0[s & 3] = nbrsT[(size_t)(k0 + s + 4) * NT_STRIDE + r0];
            id1[s & 3] = nbrsT[(size_t)(k0 + s + 4) * NT_STRIDE + r1];
        }
        if (s + 2 < 14) {                      // A-gather prefetch for s+2
            const int j = (s + 2) & 3;
            const int st = (s + 2) % 3;
            const bf16x8* p0 = (const bf16x8*)(xb + (size_t)id0[j] * 64);
            const bf16x8* p1 = (const bf16x8*)(xb + (size_t)id1[j] * 64);
            apf[st][0] = p0[lgrp]; apf[st][1] = p0[4 + lgrp];
            apf[st][2] = p1[lgrp]; apf[st][3] = p1[4 + lgrp];
        }
        __builtin_amdgcn_sched_barrier(0);     // pin: prefetch issue stays ahead of MFMA block
        const int st = s % 3;
        const bf16x8* wk = wp + (size_t)(k0 + s) * 512 + lane;
        {   // kk = 0 (c 0..31)
            bf16x8 b0 = wk[0], b1 = wk[64], b2 = wk[128], b3 = wk[192];
            acc[0][0] = __builtin_amdgcn_mfma_f32_16x16x32_bf16(apf[st][0], b0, acc[0][0], 0, 0, 0);
            acc[1][0] = __builtin_amdgcn_mfma_f32_16x16x32_bf16(apf[st][2], b0, acc[1][0], 0, 0, 0);
            acc[0][1] = __builtin_amdgcn_mfma_f32_16x16x32_bf16(apf[st][0], b1, acc[0][1], 0, 0, 0);
            acc[1][1] = __builtin_amdgcn_mfma_f32_16x16x32_bf16(apf[st][2], b1, acc[1][1], 0, 0, 0);
            acc[0][2] = __builtin_amdgcn_mfma_f32_16x16x32_bf16(apf[st][0], b2, acc[0][2], 0, 0, 0);
            acc[1][2] = __builtin_amdgcn_mfma_f32_16x16x32_bf16(apf[st][2], b2, acc[1][2], 0, 0, 0);
            acc[0][3] = __builtin_amdgcn_mfma_f32_16x16x32_bf16(apf[st][0], b3, acc[0][3], 0, 0, 0);
            acc[1][3] = __builtin_amdgcn_mfma_f32_16x16x32_bf16(apf[st][2], b3, acc[1][3], 0, 0, 0);
        }
        {   // kk = 1 (c 32..63)
            bf16x8 b0 = wk[256], b1 = wk[320], b2 = wk[384], b3 = wk[448];
            acc[0][0] = __builtin_amdgcn_mfma_f32_16x16x32_bf16(apf[st][1], b0, acc[0][0], 0, 0, 0);
            acc[1][0] = __builtin_amdgcn_mfma_f32_16x16x32_bf16(apf[st][3], b0, acc[1][0], 0, 0, 0);
            acc[0][1] = __builtin_amdgcn_mfma_f32_16x16x32_bf16(apf[st][1], b1, acc[0][1], 0, 0, 0);
            acc[1][1] = __builtin_amdgcn_mfma_f32_16x16x32_bf16(apf[st][3], b1, acc[1][1], 0, 0, 0);
            acc[0][2] = __builtin_amdgcn_mfma_f32_16x16x32_bf16(apf[st][1], b2, acc[0][2], 0, 0, 0);
            acc[1][2] = __builtin_amdgcn_mfma_f32_16x16x32_bf16(apf[st][3], b2, acc[1][2], 0, 0, 0);
            acc[0][3] = __builtin_amdgcn_mfma_f32_16x16x32_bf16(apf[st][1], b3, acc[0][3], 0, 0, 0);
            acc[1][3] = __builtin_amdgcn_mfma_f32_16x16x32_bf16(apf[st][3], b3, acc[1][3], 0, 0, 0);
        }
    }

    // ---- K-half reduction through LDS f32 tile (row stride 68 keeps 16B alignment, 2-way banks) ----
    __shared__ __align__(16) float ytile[64 * 68];
    __shared__ __align__(16) float sred[4][128];

    if (kh == 0) {                             // phase 1: khalf-0 waves write
#pragma unroll
        for (int m = 0; m < 2; ++m)
#pragma unroll
            for (int cb = 0; cb < 4; ++cb)
#pragma unroll
                for (int r = 0; r < 4; ++r)
                    ytile[(h * 32 + m * 16 + lgrp * 4 + r) * 68 + cb * 16 + l15] = acc[m][cb][r];
    }
    __syncthreads();
    if (kh == 1) {                             // phase 2: khalf-1 waves accumulate
#pragma unroll
        for (int m = 0; m < 2; ++m)
#pragma unroll
            for (int cb = 0; cb < 4; ++cb)
#pragma unroll
                for (int r = 0; r < 4; ++r)
                    ytile[(h * 32 + m * 16 + lgrp * 4 + r) * 68 + cb * 16 + l15] += acc[m][cb][r];
    }
    __syncthreads();

    // ---- phase 3: coalesced read-out -> bf16 y store + per-channel sum/sumsq ----
    const int row = tid >> 2;                  // 0..63
    const int colb = (tid & 3) * 16;           // 0,16,32,48
    f32x4 v[4];
#pragma unroll
    for (int j = 0; j < 4; ++j) v[j] = *(const f32x4*)&ytile[row * 68 + colb + 4 * j];

    const int grow = blockIdx.x * 64 + row;
    if (grow < N_PTS) {
        u16x8 o0, o1;
#pragma unroll
        for (int j = 0; j < 4; ++j) { o0[j] = f2bf(v[0][j]); o0[4 + j] = f2bf(v[1][j]); }
#pragma unroll
        for (int j = 0; j < 4; ++j) { o1[j] = f2bf(v[2][j]); o1[4 + j] = f2bf(v[3][j]); }
        *(u16x8*)(ybf + (size_t)grow * 64 + colb) = o0;
        *(u16x8*)(ybf + (size_t)grow * 64 + colb + 8) = o1;
    }

    f32x4 sv[4], s2v[4];
#pragma unroll
    for (int j = 0; j < 4; ++j) { sv[j] = v[j]; s2v[j] = v[j] * v[j]; }
#pragma unroll
    for (int off = 4; off < 64; off <<= 1) {
#pragma unroll
        for (int j = 0; j < 4; ++j) {
#pragma unroll
            for (int e = 0; e < 4; ++e) {
                sv[j][e]  += __shfl_xor(sv[j][e],  off);
                s2v[j][e] += __shfl_xor(s2v[j][e], off);
            }
        }
    }
    if (lane < 4) {                            // lane c holds sums for cols c*16..c*16+15 of its wave's 16 rows
#pragma unroll
        for (int j = 0; j < 4; ++j) {
            *(f32x4*)&sred[wave][lane * 16 + 4 * j]      = sv[j];
            *(f32x4*)&sred[wave][64 + lane * 16 + 4 * j] = s2v[j];
        }
    }
    __syncthreads();
    if (tid < 128) {
        float p = sred[0][tid] + sred[1][tid] + sred[2][tid] + sred[3][tid];
        partials[(size_t)blockIdx.x * 128 + tid] = p;
    }
}

// ---------------- BN finalize: 64 blocks, one channel each ----------------
__global__ void bn_fin_k(const float* __restrict__ partials,
                         const float* __restrict__ gamma,
                         const float* __restrict__ beta,
                         float* __restrict__ scsh) {
    const int c = blockIdx.x;                  // 0..63
    const int t = threadIdx.x;                 // 256
    float s = 0.f, s2 = 0.f;
    for (int w = t; w < NB_CONV; w += 256) {
        s  += partials[(size_t)w * 128 + c];
        s2 += partials[(size_t)w * 128 + 64 + c];
    }
#pragma unroll
    for (int off = 1; off < 64; off <<= 1) {
        s  += __shfl_xor(s, off, 64);
        s2 += __shfl_xor(s2, off, 64);
    }
    __shared__ float sm[8];
    int wv = t >> 6;
    if ((t & 63) == 0) { sm[wv] = s; sm[4 + wv] = s2; }
    __syncthreads();
    if (t == 0) {
        float S  = sm[0] + sm[1] + sm[2] + sm[3];
        float S2 = sm[4] + sm[5] + sm[6] + sm[7];
        const float invN = 1.0f / (float)N_PTS;
        float mu = S * invN;
        float var = S2 * invN - mu * mu;
        float sc = gamma[c] * rsqrtf(var + 1e-4f);
        scsh[c] = sc;
        scsh[64 + c] = beta[c] - mu * sc;
    }
}

// ---------------- BN + ReLU -> bf16 (input to next conv) ----------------
__global__ void bn_relu_cast_k(const unsigned short* __restrict__ ybf, const float* __restrict__ scsh,
                               unsigned short* __restrict__ xb) {
    int t = blockIdx.x * 256 + threadIdx.x;
    if (t >= TOTAL / 8) return;
    int i = t * 8;
    int c0 = i & 63;
    u16x8 v = *(const u16x8*)(ybf + i);
    f32x4 sa = *(const f32x4*)(scsh + c0);
    f32x4 sb = *(const f32x4*)(scsh + c0 + 4);
    f32x4 ba = *(const f32x4*)(scsh + 64 + c0);
    f32x4 bb = *(const f32x4*)(scsh + 64 + c0 + 4);
    u16x8 o;
#pragma unroll
    for (int j = 0; j < 4; ++j) {
        o[j]     = f2bf(fmaxf(bf2f(v[j])     * sa[j] + ba[j], 0.f));
        o[4 + j] = f2bf(fmaxf(bf2f(v[4 + j]) * sb[j] + bb[j], 0.f));
    }
    *(u16x8*)(xb + i) = o;
}

// ---------------- BN + residual + ReLU -> f32 out (+ bf16 for next conv) ----------------
__global__ void bn_add_relu_k(const unsigned short* __restrict__ ybf, const float* __restrict__ scsh,
                              const float* __restrict__ res, float* __restrict__ xout,
                              unsigned short* __restrict__ xb, int writeBf) {
    int t = blockIdx.x * 256 + threadIdx.x;
    if (t >= TOTAL / 8) return;
    int i = t * 8;
    int c0 = i & 63;
    u16x8 v = *(const u16x8*)(ybf + i);
    f32x4 q0 = ((const f32x4*)(res + i))[0];
    f32x4 q1 = ((const f32x4*)(res + i))[1];
    f32x4 sa = *(const f32x4*)(scsh + c0);
    f32x4 sb = *(const f32x4*)(scsh + c0 + 4);
    f32x4 ba = *(const f32x4*)(scsh + 64 + c0);
    f32x4 bb = *(const f32x4*)(scsh + 64 + c0 + 4);
    f32x4 o0, o1;
#pragma unroll
    for (int j = 0; j < 4; ++j) {
        o0[j] = fmaxf(bf2f(v[j])     * sa[j] + ba[j] + q0[j], 0.f);
        o1[j] = fmaxf(bf2f(v[4 + j]) * sb[j] + bb[j] + q1[j], 0.f);
    }
    ((f32x4*)(xout + i))[0] = o0;
    ((f32x4*)(xout + i))[1] = o1;
    if (writeBf) {
        u16x8 o;
#pragma unroll
        for (int j = 0; j < 4; ++j) { o[j] = f2bf(o0[j]); o[4 + j] = f2bf(o1[j]); }
        *(u16x8*)(xb + i) = o;
    }
}

extern "C" void kernel_launch(void* const* d_in, const int* in_sizes, int n_in,
                              void* d_out, int out_size, void* d_ws, size_t ws_size,
                              hipStream_t stream) {
    const float* feats = (const float*)d_in[0];
    const int*   nbrs  = (const int*)d_in[1];
    const float* W     = (const float*)d_in[2];
    const float* gamma = (const float*)d_in[3];
    const float* beta  = (const float*)d_in[4];
    float* out = (float*)d_out;

    char* ws = (char*)d_ws;
    unsigned short* xb       = (unsigned short*)ws;              // 12,800,128 B
    unsigned short* ybf      = (unsigned short*)(ws + 12800512); // 12,800,000 B
    unsigned short* Wp       = (unsigned short*)(ws + 25600512); //    917,504 B (4 x 28 x 4096 x 2)
    int*            nbrsT    = (int*)(ws + 26518016);            // 11,210,752 B (28 x 100096 x 4)
    float*          partials = (float*)(ws + 37728768);          //    800,768 B
    float*          scsh     = (float*)(ws + 38529536);          //        512 B

    dim3 b256(256);
    cast_in_k<<<((N_PTS + 1) * 8 + 255) / 256, b256, 0, stream>>>(feats, xb);
    tr_nbrs_k<<<NT_STRIDE / 64, b256, 0, stream>>>(nbrs, nbrsT);
    pack_w_k<<<(4 * NKP * 4096) / 256, b256, 0, stream>>>(W, Wp);

    const int appl_blocks = (TOTAL / 8) / 256;  // 3125
    for (int blk = 0; blk < 2; ++blk) {
        int c0 = blk * 2, c1 = blk * 2 + 1;
        conv_k<<<NB_CONV, b256, 0, stream>>>(xb, nbrsT, Wp + (size_t)c0 * NKP * 4096, ybf, partials);
        bn_fin_k<<<64, b256, 0, stream>>>(partials, gamma + c0 * 64, beta + c0 * 64, scsh);
        bn_relu_cast_k<<<appl_blocks, b256, 0, stream>>>(ybf, scsh, xb);
        conv_k<<<NB_CONV, b256, 0, stream>>>(xb, nbrsT, Wp + (size_t)c1 * NKP * 4096, ybf, partials);
        bn_fin_k<<<64, b256, 0, stream>>>(partials, gamma + c1 * 64, beta + c1 * 64, scsh);
        const float* res = (blk == 0) ? feats : (const float*)out;
        bn_add_relu_k<<<appl_blocks, b256, 0, stream>>>(ybf, scsh, res, out, xb, blk == 0 ? 1 : 0);
    }
}